// Round 5
// baseline (1899.965 us; speedup 1.0000x reference)
//
#include <hip/hip_runtime.h>
#include <math.h>

typedef short bf16x8_t __attribute__((ext_vector_type(8)));
typedef float f32x4_t  __attribute__((ext_vector_type(4)));

__device__ __forceinline__ float fast_rcp(float x) { return __builtin_amdgcn_rcpf(x); }
__device__ __forceinline__ float sigmoidf_(float x) {
  return fast_rcp(1.0f + __expf(-x));
}
__device__ __forceinline__ float tanhf_(float x) {
  return fmaf(-2.0f, fast_rcp(__expf(2.0f * x) + 1.0f), 1.0f);
}
__device__ __forceinline__ unsigned short f2bf(float f) {
  unsigned int u = __float_as_uint(f);
  unsigned int r = (u + 0x7fffu + ((u >> 16) & 1u)) >> 16;
  return (unsigned short)r;
}
__device__ __forceinline__ float bf2f(unsigned short u) {
  return __uint_as_float(((unsigned int)u) << 16);
}

// ---------- dense 32-in/32-out linear: out = [relu?](X) @ W^T + b ----------
template<bool RELU_IN, bool OUT_BF16>
__global__ __launch_bounds__(256) void lin32_kernel(
    const float* __restrict__ X, const float* __restrict__ W,
    const float* __restrict__ b, void* __restrict__ outp, int N)
{
  __shared__ float sW[32][33];
  __shared__ float sb[32];
  __shared__ float sX[8][33];
  const int tid = threadIdx.x;
  for (int i = tid; i < 1024; i += 256) sW[i >> 5][i & 31] = W[i];
  if (tid < 32) sb[tid] = b[tid];
  const int n0 = blockIdx.x * 8;
  {
    float v = X[(size_t)n0 * 32 + tid];
    if (RELU_IN) v = fmaxf(v, 0.0f);
    sX[tid >> 5][tid & 31] = v;
  }
  __syncthreads();
  const int ln = tid >> 5, f = tid & 31;
  float acc = sb[f];
  #pragma unroll
  for (int j = 0; j < 32; j++) acc += sX[ln][j] * sW[f][j];
  if (OUT_BF16) ((unsigned short*)outp)[(size_t)n0 * 32 + tid] = f2bf(acc);
  else          ((float*)outp)[(size_t)n0 * 32 + tid] = acc;
}

// ---------- fallback SpMM (atomics, fp32) ----------
__global__ __launch_bounds__(256) void spmm_kernel(
    const int* __restrict__ erow, const int* __restrict__ ecol,
    const float* __restrict__ eval, const float* __restrict__ X,
    float* __restrict__ out, int E)
{
  const long gid = (long)blockIdx.x * 256 + threadIdx.x;
  const int e = (int)(gid >> 3);
  const int q = (int)(gid & 7);
  if (e >= E) return;
  const int r = erow[e], c = ecol[e];
  const float v = eval[e];
  const float4 x = *(const float4*)(X + (size_t)c * 32 + q * 4);
  float* o = out + (size_t)r * 32 + q * 4;
  atomicAdd(o + 0, v * x.x);
  atomicAdd(o + 1, v * x.y);
  atomicAdd(o + 2, v * x.z);
  atomicAdd(o + 3, v * x.w);
}

// ================= bucketed SpMM pipeline =================
// bucket = 128 consecutive rows; pairs pack (row_local<<17 | col, val_f32)
#define BKT_SH    7
#define BKT_ROWS  128
#define NBKT_MAX  784
#define BIN_CAP   16

// coarse histogram, LDS-aggregated
__global__ __launch_bounds__(256) void bkthist_k(
    const int* __restrict__ erow, int* __restrict__ bktcnt,
    int E, int per_block, int nbkt)
{
  __shared__ int cnt[NBKT_MAX];
  const int tid = threadIdx.x;
  for (int b = tid; b < nbkt; b += 256) cnt[b] = 0;
  __syncthreads();
  const int e0 = blockIdx.x * per_block;
  const int e1 = min(E, e0 + per_block);
  for (int e = e0 + tid; e < e1; e += 256)
    atomicAdd(&cnt[erow[e] >> BKT_SH], 1);
  __syncthreads();
  for (int b = tid; b < nbkt; b += 256)
    if (cnt[b]) atomicAdd(&bktcnt[b], cnt[b]);
}

// exclusive scan of 8-padded counts -> 64B-aligned bucket bases (single block)
__global__ __launch_bounds__(1024) void bktscan_k(
    const int* __restrict__ bktcnt, int* __restrict__ basep,
    int* __restrict__ cursor, int nbkt)
{
  __shared__ int s[1024];
  const int t = threadIdx.x;
  int c = (t < nbkt) ? ((bktcnt[t] + 7) & ~7) : 0;
  s[t] = c; __syncthreads();
  for (int off = 1; off < 1024; off <<= 1) {
    int u = (t >= off) ? s[t - off] : 0;
    __syncthreads(); s[t] += u; __syncthreads();
  }
  if (t < nbkt) { int b = s[t] - c; basep[t] = b; cursor[t] = b; }
}

// staged binned scatter: LDS bins, flush full 64B lines to bucket regions
__global__ __launch_bounds__(256) void scat_bin_k(
    const int* __restrict__ erow, const int* __restrict__ ecol,
    const float* __restrict__ evl, int* __restrict__ cursor,
    int2* __restrict__ pairs, int E, int per_block, int nbkt)
{
  __shared__ int2 bins[NBKT_MAX][BIN_CAP];
  __shared__ int binCnt[NBKT_MAX];
  const int tid = threadIdx.x;
  for (int b = tid; b < nbkt; b += 256) binCnt[b] = 0;
  __syncthreads();
  const int e0 = blockIdx.x * per_block;
  const int e1 = min(E, e0 + per_block);
  for (int eb = e0; eb < e1; eb += 256) {
    const int e = eb + tid;
    if (e < e1) {
      const int r = erow[e];
      const int key = ((r & (BKT_ROWS - 1)) << 17) | ecol[e];
      const int vb = __float_as_int(evl[e]);
      const int bkt = r >> BKT_SH;
      const int slot = atomicAdd(&binCnt[bkt], 1);
      if (slot < BIN_CAP) {
        bins[bkt][slot] = make_int2(key, vb);
      } else {
        atomicSub(&binCnt[bkt], 1);
        int p = atomicAdd(&cursor[bkt], 1);
        pairs[p] = make_int2(key, vb);
      }
    }
    __syncthreads();
    // flush multiples of 8 pairs (= full 64B lines; bases are 8-aligned)
    for (int b = tid; b < nbkt; b += 256) {
      const int c = binCnt[b];
      const int fl = c & ~7;
      if (fl > 0) {
        int gp = atomicAdd(&cursor[b], fl);
        for (int i = 0; i < fl; i += 2)
          *(int4*)&pairs[gp + i] = *(int4*)&bins[b][i];
        const int rem = c - fl;
        for (int i = 0; i < rem; i++) bins[b][i] = bins[b][fl + i];
        binCnt[b] = rem;
      }
    }
    __syncthreads();
  }
  // drain remainders (partial lines, bounded: <8 pairs per (block,bucket))
  for (int b = tid; b < nbkt; b += 256) {
    const int c = binCnt[b];
    if (c > 0) {
      int gp = atomicAdd(&cursor[b], c);
      for (int i = 0; i < c; i++) pairs[gp + i] = bins[b][i];
    }
  }
}

// SpMM: one block per bucket; LDS fp32 accumulator; feature-per-lane ds_add
__global__ __launch_bounds__(256) void spmm_bkt_k(
    const int* __restrict__ basep, const int* __restrict__ bktcnt,
    const int2* __restrict__ pairs, const unsigned short* __restrict__ X,
    float* __restrict__ out, int N)
{
  __shared__ float acc[BKT_ROWS][33];   // stride 33: bank = (row+f)%32, conflict-free
  const int tid = threadIdx.x;
  const int b = blockIdx.x;
  const int g = tid >> 5;               // 8 groups of 32 lanes
  const int f = tid & 31;
  for (int i = tid; i < BKT_ROWS * 33; i += 256) ((float*)acc)[i] = 0.0f;
  __syncthreads();
  const int eb = basep[b], cnt = bktcnt[b];
  int i = g;
  for (; i + 24 < cnt; i += 32) {
    int2 p0 = pairs[eb + i];
    int2 p1 = pairs[eb + i + 8];
    int2 p2 = pairs[eb + i + 16];
    int2 p3 = pairs[eb + i + 24];
    float x0 = bf2f(X[(size_t)(p0.x & 0x1FFFF) * 32 + f]);
    float x1 = bf2f(X[(size_t)(p1.x & 0x1FFFF) * 32 + f]);
    float x2 = bf2f(X[(size_t)(p2.x & 0x1FFFF) * 32 + f]);
    float x3 = bf2f(X[(size_t)(p3.x & 0x1FFFF) * 32 + f]);
    atomicAdd(&acc[p0.x >> 17][f], __int_as_float(p0.y) * x0);
    atomicAdd(&acc[p1.x >> 17][f], __int_as_float(p1.y) * x1);
    atomicAdd(&acc[p2.x >> 17][f], __int_as_float(p2.y) * x2);
    atomicAdd(&acc[p3.x >> 17][f], __int_as_float(p3.y) * x3);
  }
  for (; i < cnt; i += 8) {
    int2 p = pairs[eb + i];
    float x = bf2f(X[(size_t)(p.x & 0x1FFFF) * 32 + f]);
    atomicAdd(&acc[p.x >> 17][f], __int_as_float(p.y) * x);
  }
  __syncthreads();
  const int r0 = b << BKT_SH;
  for (int rr = tid >> 5; rr < BKT_ROWS; rr += 8) {
    const int row = r0 + rr;
    if (row < N) out[(size_t)row * 32 + f] = acc[rr][f];
  }
}

// ---------- fused MFMA GRU + head, 32 nodes / block (unchanged from R4) ----------
#define NB 32

__global__ __launch_bounds__(256, 2) void gru_head_mfma(
    const float* __restrict__ acc2, const float* __restrict__ xdyn,
    const float* __restrict__ Wih, const float* __restrict__ Whh,
    const float* __restrict__ bih, const float* __restrict__ bhh,
    const float* __restrict__ h1W, const float* __restrict__ h1b,
    const float* __restrict__ h2W, const float* __restrict__ h2b,
    float* __restrict__ out, int N, int T)
{
  __shared__ __align__(16) unsigned short z[2][NB][104];
  __shared__ float s_red[2][NB][5];

  const int tid  = threadIdx.x;
  const int w    = tid >> 6;
  const int lane = tid & 63;
  const int ml   = lane & 15;
  const int q    = lane >> 4;
  const int n0   = blockIdx.x * NB;

  bf16x8_t A_r[3], A_z[3], A_in, A_hn[2];
  {
    const int j = 16 * w + ml;
    #pragma unroll
    for (int s = 0; s < 3; s++) {
      union { bf16x8_t v; unsigned short u[8]; } tr, tz;
      #pragma unroll
      for (int jj = 0; jj < 8; jj++) {
        int k = s * 32 + q * 8 + jj;
        float vr = (k < 64) ? Whh[j * 64 + k]        : (k < 72 ? Wih[j * 40 + 32 + (k - 64)] : 0.0f);
        float vz = (k < 64) ? Whh[(64 + j) * 64 + k] : (k < 72 ? Wih[(64 + j) * 40 + 32 + (k - 64)] : 0.0f);
        tr.u[jj] = f2bf(vr);
        tz.u[jj] = f2bf(vz);
      }
      A_r[s] = tr.v; A_z[s] = tz.v;
    }
    union { bf16x8_t v; unsigned short u[8]; } ti;
    #pragma unroll
    for (int jj = 0; jj < 8; jj++) {
      int kk = q * 8 + jj;
      ti.u[jj] = f2bf((kk < 8) ? Wih[(128 + j) * 40 + 32 + kk] : 0.0f);
    }
    A_in = ti.v;
    #pragma unroll
    for (int s = 0; s < 2; s++) {
      union { bf16x8_t v; unsigned short u[8]; } th;
      #pragma unroll
      for (int jj = 0; jj < 8; jj++)
        th.u[jj] = f2bf(Whh[(128 + j) * 64 + s * 32 + q * 8 + jj]);
      A_hn[s] = th.v;
    }
  }
  bf16x8_t Ah[2];
  #pragma unroll
  for (int s = 0; s < 2; s++) {
    union { bf16x8_t v; unsigned short u[8]; } tmp;
    #pragma unroll
    for (int jj = 0; jj < 8; jj++)
      tmp.u[jj] = f2bf(h1W[(16 * w + ml) * 64 + s * 32 + q * 8 + jj]);
    Ah[s] = tmp.v;
  }

  float bhh_n[4], h1b_r[4], h2w_r[4];
  #pragma unroll
  for (int reg = 0; reg < 4; reg++) {
    int j = 16 * w + 4 * q + reg;
    bhh_n[reg] = bhh[128 + j];
    h1b_r[reg] = h1b[j];
    h2w_r[reg] = h2W[j];
  }
  const float h2b0 = h2b[0];

  {
    int nd = tid >> 3, f0 = (tid & 7) * 4;
    float4 v = *(const float4*)(acc2 + (size_t)(n0 + nd) * 32 + f0);
    unsigned long long pk =
        (unsigned long long)f2bf(fmaxf(v.x, 0.0f)) |
        ((unsigned long long)f2bf(fmaxf(v.y, 0.0f)) << 16) |
        ((unsigned long long)f2bf(fmaxf(v.z, 0.0f)) << 32) |
        ((unsigned long long)f2bf(fmaxf(v.w, 0.0f)) << 48);
    *(unsigned long long*)&z[0][nd][f0] = pk;
  }
  __syncthreads();

  f32x4_t gis[3][2];
  {
    bf16x8_t Ag[3];
    #pragma unroll
    for (int g = 0; g < 3; g++) {
      union { bf16x8_t v; unsigned short u[8]; } tmp;
      #pragma unroll
      for (int jj = 0; jj < 8; jj++)
        tmp.u[jj] = f2bf(Wih[(g * 64 + 16 * w + ml) * 40 + q * 8 + jj]);
      Ag[g] = tmp.v;
    }
    bf16x8_t Bg[2];
    #pragma unroll
    for (int nt = 0; nt < 2; nt++)
      Bg[nt] = *(const bf16x8_t*)&z[0][nt * 16 + ml][q * 8];
    f32x4_t zero = {0.0f, 0.0f, 0.0f, 0.0f};
    #pragma unroll
    for (int g = 0; g < 3; g++)
      #pragma unroll
      for (int nt = 0; nt < 2; nt++)
        gis[g][nt] = __builtin_amdgcn_mfma_f32_16x16x32_bf16(Ag[g], Bg[nt], zero, 0, 0, 0);
  }
  __syncthreads();

  for (int i = tid; i < 2 * NB * 104 / 2; i += 256) ((unsigned int*)z)[i] = 0;
  #pragma unroll
  for (int reg = 0; reg < 4; reg++) {
    int j = 16 * w + 4 * q + reg;
    float br = bih[j] + bhh[j];
    float bz = bih[64 + j] + bhh[64 + j];
    float bn = bih[128 + j];
    #pragma unroll
    for (int nt = 0; nt < 2; nt++) {
      gis[0][nt][reg] += br;
      gis[1][nt][reg] += bz;
      gis[2][nt][reg] += bn;
    }
  }
  __syncthreads();

  float hreg[2][4] = {{0, 0, 0, 0}, {0, 0, 0, 0}};

  float4 xv = make_float4(0.f, 0.f, 0.f, 0.f);
  if (tid < 64) xv = *(const float4*)(xdyn + (size_t)n0 * 8 + tid * 4);

  for (int t = 0; t < T; t++) {
    const int b = t & 1;
    if (tid < 64) {
      unsigned long long pk =
          (unsigned long long)f2bf(xv.x) |
          ((unsigned long long)f2bf(xv.y) << 16) |
          ((unsigned long long)f2bf(xv.z) << 32) |
          ((unsigned long long)f2bf(xv.w) << 48);
      *(unsigned long long*)&z[b][tid >> 1][64 + (tid & 1) * 4] = pk;
      if (t + 1 < T)
        xv = *(const float4*)(xdyn + ((size_t)(t + 1) * N + n0) * 8 + tid * 4);
    }
    __syncthreads();

    if (t >= 2 && tid < 32) {
      float s = s_red[1 - b][tid][0] + s_red[1 - b][tid][1] +
                s_red[1 - b][tid][2] + s_red[1 - b][tid][3];
      out[(size_t)(t - 2) * N + n0 + tid] = sigmoidf_(s + h2b0);
    }

    #pragma unroll
    for (int nt = 0; nt < 2; nt++) {
      bf16x8_t B0 = *(const bf16x8_t*)&z[b][nt * 16 + ml][q * 8];
      bf16x8_t B1 = *(const bf16x8_t*)&z[b][nt * 16 + ml][32 + q * 8];
      bf16x8_t B2 = *(const bf16x8_t*)&z[b][nt * 16 + ml][64 + q * 8];

      f32x4_t ar = {0.f, 0.f, 0.f, 0.f}, az = ar, ain = ar, ahn = ar;
      ar  = __builtin_amdgcn_mfma_f32_16x16x32_bf16(A_r[0], B0, ar, 0, 0, 0);
      az  = __builtin_amdgcn_mfma_f32_16x16x32_bf16(A_z[0], B0, az, 0, 0, 0);
      ahn = __builtin_amdgcn_mfma_f32_16x16x32_bf16(A_hn[0], B0, ahn, 0, 0, 0);
      ar  = __builtin_amdgcn_mfma_f32_16x16x32_bf16(A_r[1], B1, ar, 0, 0, 0);
      az  = __builtin_amdgcn_mfma_f32_16x16x32_bf16(A_z[1], B1, az, 0, 0, 0);
      ahn = __builtin_amdgcn_mfma_f32_16x16x32_bf16(A_hn[1], B1, ahn, 0, 0, 0);
      ar  = __builtin_amdgcn_mfma_f32_16x16x32_bf16(A_r[2], B2, ar, 0, 0, 0);
      az  = __builtin_amdgcn_mfma_f32_16x16x32_bf16(A_z[2], B2, az, 0, 0, 0);
      ain = __builtin_amdgcn_mfma_f32_16x16x32_bf16(A_in,  B2, ain, 0, 0, 0);

      if (t >= 1) {
        f32x4_t ha = {0.f, 0.f, 0.f, 0.f};
        ha = __builtin_amdgcn_mfma_f32_16x16x32_bf16(Ah[0], B0, ha, 0, 0, 0);
        ha = __builtin_amdgcn_mfma_f32_16x16x32_bf16(Ah[1], B1, ha, 0, 0, 0);
        float p = 0.0f;
        #pragma unroll
        for (int reg = 0; reg < 4; reg++)
          p += h2w_r[reg] * fmaxf(ha[reg] + h1b_r[reg], 0.0f);
        p += __shfl_xor(p, 16, 64);
        p += __shfl_xor(p, 32, 64);
        if (q == 0) s_red[b][nt * 16 + ml][w] = p;
      }

      unsigned short hb[4];
      #pragma unroll
      for (int reg = 0; reg < 4; reg++) {
        float r  = sigmoidf_(gis[0][nt][reg] + ar[reg]);
        float zg = sigmoidf_(gis[1][nt][reg] + az[reg]);
        float hn = bhh_n[reg] + ahn[reg];
        float nn = tanhf_(gis[2][nt][reg] + ain[reg] + r * hn);
        float h  = fmaf(zg, hreg[nt][reg] - nn, nn);
        hreg[nt][reg] = h;
        hb[reg] = f2bf(h);
      }
      unsigned long long pk =
          (unsigned long long)hb[0] | ((unsigned long long)hb[1] << 16) |
          ((unsigned long long)hb[2] << 32) | ((unsigned long long)hb[3] << 48);
      *(unsigned long long*)&z[1 - b][nt * 16 + ml][16 * w + 4 * q] = pk;
    }
  }

  const int bl = (T - 1) & 1;
  __syncthreads();

  if (tid < 32) {
    float s = s_red[bl][tid][0] + s_red[bl][tid][1] +
              s_red[bl][tid][2] + s_red[bl][tid][3];
    out[(size_t)(T - 2) * N + n0 + tid] = sigmoidf_(s + h2b0);
  }
  #pragma unroll
  for (int nt = 0; nt < 2; nt++) {
    bf16x8_t B0 = *(const bf16x8_t*)&z[1 - bl][nt * 16 + ml][q * 8];
    bf16x8_t B1 = *(const bf16x8_t*)&z[1 - bl][nt * 16 + ml][32 + q * 8];
    f32x4_t ha = {0.f, 0.f, 0.f, 0.f};
    ha = __builtin_amdgcn_mfma_f32_16x16x32_bf16(Ah[0], B0, ha, 0, 0, 0);
    ha = __builtin_amdgcn_mfma_f32_16x16x32_bf16(Ah[1], B1, ha, 0, 0, 0);
    float p = 0.0f;
    #pragma unroll
    for (int reg = 0; reg < 4; reg++)
      p += h2w_r[reg] * fmaxf(ha[reg] + h1b_r[reg], 0.0f);
    p += __shfl_xor(p, 16, 64);
    p += __shfl_xor(p, 32, 64);
    if (q == 0) s_red[1 - bl][nt * 16 + ml][w] = p;
  }
  __syncthreads();
  if (tid < 32) {
    float s = s_red[1 - bl][tid][0] + s_red[1 - bl][tid][1] +
              s_red[1 - bl][tid][2] + s_red[1 - bl][tid][3];
    out[(size_t)(T - 1) * N + n0 + tid] = sigmoidf_(s + h2b0);
  }
}

extern "C" void kernel_launch(void* const* d_in, const int* in_sizes, int n_in,
                              void* d_out, int out_size, void* d_ws, size_t ws_size,
                              hipStream_t stream) {
  const float* Xs   = (const float*)d_in[0];
  const float* Xd   = (const float*)d_in[1];
  const int*   erow = (const int*)d_in[2];
  const int*   ecol = (const int*)d_in[3];
  const float* evl  = (const float*)d_in[4];
  const float* g1W  = (const float*)d_in[5];
  const float* g1b  = (const float*)d_in[6];
  const float* g2W  = (const float*)d_in[7];
  const float* g2b  = (const float*)d_in[8];
  const float* Wih  = (const float*)d_in[9];
  const float* Whh  = (const float*)d_in[10];
  const float* bih  = (const float*)d_in[11];
  const float* bhh  = (const float*)d_in[12];
  const float* h1W  = (const float*)d_in[13];
  const float* h1b  = (const float*)d_in[14];
  const float* h2W  = (const float*)d_in[15];
  const float* h2b  = (const float*)d_in[16];

  const int N = in_sizes[0] / 32;
  const int E = in_sizes[2];
  const int T = in_sizes[1] / (N * 8);

  float* out  = (float*)d_out;
  char*  base = (char*)d_ws;
  float* buf0 = (float*)base;                         // N*32 f32 (bf16 aliased)
  float* buf1 = buf0 + (size_t)N * 32;                // N*32 f32
  const int nbkt = (N + BKT_ROWS - 1) >> BKT_SH;
  int2*  pairs  = (int2*)(buf1 + (size_t)N * 32);     // E + 8*nbkt
  int*   bktcnt = (int*)(pairs + (size_t)E + 8 * (size_t)nbkt);
  int*   basep  = bktcnt + nbkt;
  int*   cursor = basep + nbkt;
  unsigned short* buf0h = (unsigned short*)buf0;

  const size_t needed = (size_t)((char*)(cursor + nbkt) - base);
  const bool use_bkt = (ws_size >= needed) && (nbkt <= NBKT_MAX) && (N <= (1 << 17));

  const int linBlocks = (N + 7) / 8;
  const int perb = (E + 255) / 256;   // edges per block for 256-block sweeps

  if (use_bkt) {
    lin32_kernel<false, true><<<linBlocks, 256, 0, stream>>>(Xs, g1W, g1b, buf0h, N);

    hipMemsetAsync(bktcnt, 0, (size_t)nbkt * sizeof(int), stream);
    bkthist_k<<<256, 256, 0, stream>>>(erow, bktcnt, E, perb, nbkt);
    bktscan_k<<<1, 1024, 0, stream>>>(bktcnt, basep, cursor, nbkt);
    scat_bin_k<<<256, 256, 0, stream>>>(erow, ecol, evl, cursor, pairs, E, perb, nbkt);

    spmm_bkt_k<<<nbkt, 256, 0, stream>>>(basep, bktcnt, pairs, buf0h, buf1, N);
    lin32_kernel<true, true><<<linBlocks, 256, 0, stream>>>(buf1, g2W, g2b, buf0h, N);
    spmm_bkt_k<<<nbkt, 256, 0, stream>>>(basep, bktcnt, pairs, buf0h, buf1, N);
  } else {
    lin32_kernel<false, false><<<linBlocks, 256, 0, stream>>>(Xs, g1W, g1b, buf0, N);
    const int spmmBlocks = (int)(((long)E * 8 + 255) / 256);
    hipMemsetAsync(buf1, 0, (size_t)N * 32 * sizeof(float), stream);
    spmm_kernel<<<spmmBlocks, 256, 0, stream>>>(erow, ecol, evl, buf0, buf1, E);
    lin32_kernel<true, false><<<linBlocks, 256, 0, stream>>>(buf1, g2W, g2b, buf0, N);
    hipMemsetAsync(buf1, 0, (size_t)N * 32 * sizeof(float), stream);
    spmm_kernel<<<spmmBlocks, 256, 0, stream>>>(erow, ecol, evl, buf0, buf1, E);
  }

  gru_head_mfma<<<N / NB, 256, 0, stream>>>(buf1, Xd, Wih, Whh, bih, bhh,
                                            h1W, h1b, h2W, h2b, out, N, T);
}